// Round 6
// baseline (80.825 us; speedup 1.0000x reference)
//
#include <hip/hip_runtime.h>

#define C 128
#define DEG 32
#define NPIECES 5

typedef __fp16 h2 __attribute__((ext_vector_type(2)));

// Packed compare-and-swap: sorts both f16 lanes (2 channels) at once.
// CD: descending (a keeps max); CA: ascending (a keeps min).
#define CD(a,b) { h2 _mx = __builtin_elementwise_max(v##a, v##b); \
                  v##b   = __builtin_elementwise_min(v##a, v##b); v##a = _mx; }
#define CA(a,b) { h2 _mn = __builtin_elementwise_min(v##a, v##b); \
                  v##b   = __builtin_elementwise_max(v##a, v##b); v##a = _mn; }

// Gather one float2 (channels 2*c2, 2*c2+1) from neighbor row IDX (VGPR,
// same value in all lanes -> coalesced 512B), pack to f16x2, PIN in VGPR.
#define GATH(i, IDX) h2 v##i; { \
    float2 _f = xp[(IDX) * 64 + c2]; \
    v##i = __builtin_amdgcn_cvt_pkrtz(_f.x, _f.y); \
    asm volatile("" : "+v"(v##i)); }

#define ACC(i) { float2 _w2 = *(const float2*)(&w_s[i][2 * c2]); \
    acc0 = fmaf((float)v##i[0], _w2.x, acc0); \
    acc1 = fmaf((float)v##i[1], _w2.y, acc1); }

__global__ __launch_bounds__(256, 4) void fspool_kernel(
    const float* __restrict__ x,
    const int* __restrict__ col,
    const float* __restrict__ weight,
    float* __restrict__ out,
    int N, int nwaves)
{
    __shared__ float w_s[DEG][C];   // 16 KB: w[j][c], identical for all nodes

    const int tid = threadIdx.x;

    // ---- Precompute piecewise-linear weights w[j][c] once per block ----
    for (int p = tid; p < DEG * C; p += 256) {
        int j = p >> 7;
        int c = p & (C - 1);
        float t = (float)j / 31.0f;                 // n==32 for every node
        float index = (float)NPIECES * fminf(t, 1.0f);
        float fidx = floorf(index);
        int idx = (int)fidx;
        float frac = index - fidx;
        int idx2 = (idx + 1 > NPIECES) ? NPIECES : (idx + 1);
        float wv = (1.0f - frac) * weight[c * (NPIECES + 1) + idx]
                 + frac         * weight[c * (NPIECES + 1) + idx2];
        w_s[j][c] = wv;
    }
    __syncthreads();                // w_s ready; loop below is barrier-free

    const int c2 = tid & 63;        // channel pair: channels 2*c2, 2*c2+1
    const int wave = blockIdx.x * 4 + (tid >> 6);   // global wave id
    const float2* xp  = (const float2*)x;
    const int4*  colq = (const int4*)col;           // 4 indices per load

    for (int node = wave; node < N; node += nwaves) {
        // ---- 8 broadcast int4 loads: this node's 32 neighbor indices ----
        const int nb = node * 8;
        int4 q0 = colq[nb + 0]; int4 q1 = colq[nb + 1];
        int4 q2 = colq[nb + 2]; int4 q3 = colq[nb + 3];
        int4 q4 = colq[nb + 4]; int4 q5 = colq[nb + 5];
        int4 q6 = colq[nb + 6]; int4 q7 = colq[nb + 7];

        // ---- gather 32 float2s (1 v_mad + 1 load each), pack f16, pin ----
        GATH(0,  q0.x) GATH(1,  q0.y) GATH(2,  q0.z) GATH(3,  q0.w)
        GATH(4,  q1.x) GATH(5,  q1.y) GATH(6,  q1.z) GATH(7,  q1.w)
        GATH(8,  q2.x) GATH(9,  q2.y) GATH(10, q2.z) GATH(11, q2.w)
        GATH(12, q3.x) GATH(13, q3.y) GATH(14, q3.z) GATH(15, q3.w)
        GATH(16, q4.x) GATH(17, q4.y) GATH(18, q4.z) GATH(19, q4.w)
        GATH(20, q5.x) GATH(21, q5.y) GATH(22, q5.z) GATH(23, q5.w)
        GATH(24, q6.x) GATH(25, q6.y) GATH(26, q6.z) GATH(27, q6.w)
        GATH(28, q7.x) GATH(29, q7.y) GATH(30, q7.z) GATH(31, q7.w)

        // ---- descending bitonic sort, both channels in packed f16 ----
        // k=2
        CD(0,1) CA(2,3) CD(4,5) CA(6,7) CD(8,9) CA(10,11) CD(12,13) CA(14,15)
        CD(16,17) CA(18,19) CD(20,21) CA(22,23) CD(24,25) CA(26,27) CD(28,29) CA(30,31)
        // k=4, j=2
        CD(0,2) CD(1,3) CA(4,6) CA(5,7) CD(8,10) CD(9,11) CA(12,14) CA(13,15)
        CD(16,18) CD(17,19) CA(20,22) CA(21,23) CD(24,26) CD(25,27) CA(28,30) CA(29,31)
        // k=4, j=1
        CD(0,1) CD(2,3) CA(4,5) CA(6,7) CD(8,9) CD(10,11) CA(12,13) CA(14,15)
        CD(16,17) CD(18,19) CA(20,21) CA(22,23) CD(24,25) CD(26,27) CA(28,29) CA(30,31)
        // k=8, j=4
        CD(0,4) CD(1,5) CD(2,6) CD(3,7) CA(8,12) CA(9,13) CA(10,14) CA(11,15)
        CD(16,20) CD(17,21) CD(18,22) CD(19,23) CA(24,28) CA(25,29) CA(26,30) CA(27,31)
        // k=8, j=2
        CD(0,2) CD(1,3) CD(4,6) CD(5,7) CA(8,10) CA(9,11) CA(12,14) CA(13,15)
        CD(16,18) CD(17,19) CD(20,22) CD(21,23) CA(24,26) CA(25,27) CA(28,30) CA(29,31)
        // k=8, j=1
        CD(0,1) CD(2,3) CD(4,5) CD(6,7) CA(8,9) CA(10,11) CA(12,13) CA(14,15)
        CD(16,17) CD(18,19) CD(20,21) CD(22,23) CA(24,25) CA(26,27) CA(28,29) CA(30,31)
        // k=16, j=8
        CD(0,8) CD(1,9) CD(2,10) CD(3,11) CD(4,12) CD(5,13) CD(6,14) CD(7,15)
        CA(16,24) CA(17,25) CA(18,26) CA(19,27) CA(20,28) CA(21,29) CA(22,30) CA(23,31)
        // k=16, j=4
        CD(0,4) CD(1,5) CD(2,6) CD(3,7) CD(8,12) CD(9,13) CD(10,14) CD(11,15)
        CA(16,20) CA(17,21) CA(18,22) CA(19,23) CA(24,28) CA(25,29) CA(26,30) CA(27,31)
        // k=16, j=2
        CD(0,2) CD(1,3) CD(4,6) CD(5,7) CD(8,10) CD(9,11) CD(12,14) CD(13,15)
        CA(16,18) CA(17,19) CA(20,22) CA(21,23) CA(24,26) CA(25,27) CA(28,30) CA(29,31)
        // k=16, j=1
        CD(0,1) CD(2,3) CD(4,5) CD(6,7) CD(8,9) CD(10,11) CD(12,13) CD(14,15)
        CA(16,17) CA(18,19) CA(20,21) CA(22,23) CA(24,25) CA(26,27) CA(28,29) CA(30,31)
        // k=32, j=16
        CD(0,16) CD(1,17) CD(2,18) CD(3,19) CD(4,20) CD(5,21) CD(6,22) CD(7,23)
        CD(8,24) CD(9,25) CD(10,26) CD(11,27) CD(12,28) CD(13,29) CD(14,30) CD(15,31)
        // k=32, j=8
        CD(0,8) CD(1,9) CD(2,10) CD(3,11) CD(4,12) CD(5,13) CD(6,14) CD(7,15)
        CD(16,24) CD(17,25) CD(18,26) CD(19,27) CD(20,28) CD(21,29) CD(22,30) CD(23,31)
        // k=32, j=4
        CD(0,4) CD(1,5) CD(2,6) CD(3,7) CD(8,12) CD(9,13) CD(10,14) CD(11,15)
        CD(16,20) CD(17,21) CD(18,22) CD(19,23) CD(24,28) CD(25,29) CD(26,30) CD(27,31)
        // k=32, j=2
        CD(0,2) CD(1,3) CD(4,6) CD(5,7) CD(8,10) CD(9,11) CD(12,14) CD(13,15)
        CD(16,18) CD(17,19) CD(20,22) CD(21,23) CD(24,26) CD(25,27) CD(28,30) CD(29,31)
        // k=32, j=1
        CD(0,1) CD(2,3) CD(4,5) CD(6,7) CD(8,9) CD(10,11) CD(12,13) CD(14,15)
        CD(16,17) CD(18,19) CD(20,21) CD(22,23) CD(24,25) CD(26,27) CD(28,29) CD(30,31)

        // ---- weighted sums for both channels (f32 accumulate) ----
        float acc0 = 0.0f, acc1 = 0.0f;
        ACC(0)  ACC(1)  ACC(2)  ACC(3)  ACC(4)  ACC(5)  ACC(6)  ACC(7)
        ACC(8)  ACC(9)  ACC(10) ACC(11) ACC(12) ACC(13) ACC(14) ACC(15)
        ACC(16) ACC(17) ACC(18) ACC(19) ACC(20) ACC(21) ACC(22) ACC(23)
        ACC(24) ACC(25) ACC(26) ACC(27) ACC(28) ACC(29) ACC(30) ACC(31)

        *(float2*)(out + node * C + 2 * c2) = make_float2(acc0, acc1);
    }
}

extern "C" void kernel_launch(void* const* d_in, const int* in_sizes, int n_in,
                              void* d_out, int out_size, void* d_ws, size_t ws_size,
                              hipStream_t stream) {
    const float* x      = (const float*)d_in[0];
    const int*   edge   = (const int*)d_in[1];
    const float* weight = (const float*)d_in[2];
    float*       out    = (float*)d_out;

    int N = in_sizes[0] / C;       // 20000
    int E = in_sizes[1] / 2;       // 640000
    const int* col = edge + E;     // edge_index[1]

    const int grid = 2048;         // 8 blocks/CU, 4 waves each
    const int nwaves = grid * 4;   // one node per wave, grid-stride
    fspool_kernel<<<grid, 256, 0, stream>>>(x, col, weight, out, N, nwaves);
}

// Round 7
// 71.831 us; speedup vs baseline: 1.1252x; 1.1252x over previous
//
#include <hip/hip_runtime.h>

#define C 128
#define DEG 32
#define NPIECES 5

typedef __fp16 h2 __attribute__((ext_vector_type(2)));

// Packed compare-and-swap: sorts both f16 lanes (2 channels) at once.
// CD: descending (a keeps max); CA: ascending (a keeps min).
#define CD(a,b) { h2 _mx = __builtin_elementwise_max(v##a, v##b); \
                  v##b   = __builtin_elementwise_min(v##a, v##b); v##a = _mx; }
#define CA(a,b) { h2 _mn = __builtin_elementwise_min(v##a, v##b); \
                  v##b   = __builtin_elementwise_max(v##a, v##b); v##a = _mn; }

// Full 32-element descending bitonic network (240 comparators).
#define SORT_NET \
    CD(0,1) CA(2,3) CD(4,5) CA(6,7) CD(8,9) CA(10,11) CD(12,13) CA(14,15) \
    CD(16,17) CA(18,19) CD(20,21) CA(22,23) CD(24,25) CA(26,27) CD(28,29) CA(30,31) \
    CD(0,2) CD(1,3) CA(4,6) CA(5,7) CD(8,10) CD(9,11) CA(12,14) CA(13,15) \
    CD(16,18) CD(17,19) CA(20,22) CA(21,23) CD(24,26) CD(25,27) CA(28,30) CA(29,31) \
    CD(0,1) CD(2,3) CA(4,5) CA(6,7) CD(8,9) CD(10,11) CA(12,13) CA(14,15) \
    CD(16,17) CD(18,19) CA(20,21) CA(22,23) CD(24,25) CD(26,27) CA(28,29) CA(30,31) \
    CD(0,4) CD(1,5) CD(2,6) CD(3,7) CA(8,12) CA(9,13) CA(10,14) CA(11,15) \
    CD(16,20) CD(17,21) CD(18,22) CD(19,23) CA(24,28) CA(25,29) CA(26,30) CA(27,31) \
    CD(0,2) CD(1,3) CD(4,6) CD(5,7) CA(8,10) CA(9,11) CA(12,14) CA(13,15) \
    CD(16,18) CD(17,19) CD(20,22) CD(21,23) CA(24,26) CA(25,27) CA(28,30) CA(29,31) \
    CD(0,1) CD(2,3) CD(4,5) CD(6,7) CA(8,9) CA(10,11) CA(12,13) CA(14,15) \
    CD(16,17) CD(18,19) CD(20,21) CD(22,23) CA(24,25) CA(26,27) CA(28,29) CA(30,31) \
    CD(0,8) CD(1,9) CD(2,10) CD(3,11) CD(4,12) CD(5,13) CD(6,14) CD(7,15) \
    CA(16,24) CA(17,25) CA(18,26) CA(19,27) CA(20,28) CA(21,29) CA(22,30) CA(23,31) \
    CD(0,4) CD(1,5) CD(2,6) CD(3,7) CD(8,12) CD(9,13) CD(10,14) CD(11,15) \
    CA(16,20) CA(17,21) CA(18,22) CA(19,23) CA(24,28) CA(25,29) CA(26,30) CA(27,31) \
    CD(0,2) CD(1,3) CD(4,6) CD(5,7) CD(8,10) CD(9,11) CD(12,14) CD(13,15) \
    CA(16,18) CA(17,19) CA(20,22) CA(21,23) CA(24,26) CA(25,27) CA(28,30) CA(29,31) \
    CD(0,1) CD(2,3) CD(4,5) CD(6,7) CD(8,9) CD(10,11) CD(12,13) CD(14,15) \
    CA(16,17) CA(18,19) CA(20,21) CA(22,23) CA(24,25) CA(26,27) CA(28,29) CA(30,31) \
    CD(0,16) CD(1,17) CD(2,18) CD(3,19) CD(4,20) CD(5,21) CD(6,22) CD(7,23) \
    CD(8,24) CD(9,25) CD(10,26) CD(11,27) CD(12,28) CD(13,29) CD(14,30) CD(15,31) \
    CD(0,8) CD(1,9) CD(2,10) CD(3,11) CD(4,12) CD(5,13) CD(6,14) CD(7,15) \
    CD(16,24) CD(17,25) CD(18,26) CD(19,27) CD(20,28) CD(21,29) CD(22,30) CD(23,31) \
    CD(0,4) CD(1,5) CD(2,6) CD(3,7) CD(8,12) CD(9,13) CD(10,14) CD(11,15) \
    CD(16,20) CD(17,21) CD(18,22) CD(19,23) CD(24,28) CD(25,29) CD(26,30) CD(27,31) \
    CD(0,2) CD(1,3) CD(4,6) CD(5,7) CD(8,10) CD(9,11) CD(12,14) CD(13,15) \
    CD(16,18) CD(17,19) CD(20,22) CD(21,23) CD(24,26) CD(25,27) CD(28,30) CD(29,31) \
    CD(0,1) CD(2,3) CD(4,5) CD(6,7) CD(8,9) CD(10,11) CD(12,13) CD(14,15) \
    CD(16,17) CD(18,19) CD(20,21) CD(22,23) CD(24,25) CD(26,27) CD(28,29) CD(30,31)

// Gather for the f16 path: one dword per lane from the packed-f16 copy of x.
// Row base is SGPR (scalar col index), c2 is the only vector component. PIN.
#define GATH16(i) h2 v##i; { \
    unsigned _u = x16[(unsigned)j##i * (C/2) + c2]; \
    v##i = __builtin_bit_cast(h2, _u); \
    asm volatile("" : "+v"(v##i)); }

// Gather for the f32 fallback path (no workspace): float2 + pack.
#define GATH32(i) h2 v##i; { \
    float2 _f = xp[(unsigned)j##i * (C/2) + c2]; \
    v##i = __builtin_amdgcn_cvt_pkrtz(_f.x, _f.y); \
    asm volatile("" : "+v"(v##i)); }

#define LDIDX(i) const int j##i = cb[i];

#define ACC(i) { float2 _w2 = *(const float2*)(&w_s[i][2 * c2]); \
    acc0 = fmaf((float)v##i[0], _w2.x, acc0); \
    acc1 = fmaf((float)v##i[1], _w2.y, acc1); }

// ---- prepass: x (f32) -> packed f16x2 copy in workspace ----
__global__ __launch_bounds__(256) void cvt_kernel(
    const float* __restrict__ x, unsigned* __restrict__ x16, int total)
{
    for (int i = blockIdx.x * 256 + threadIdx.x; i < total; i += gridDim.x * 256) {
        float2 f = ((const float2*)x)[i];
        h2 h = __builtin_amdgcn_cvt_pkrtz(f.x, f.y);
        x16[i] = __builtin_bit_cast(unsigned, h);
    }
}

template <bool F16>
__global__ __launch_bounds__(256, 4) void fspool_kernel(
    const float* __restrict__ x,
    const unsigned* __restrict__ x16,
    const int* __restrict__ col,
    const float* __restrict__ weight,
    float* __restrict__ out,
    int N, int nwaves)
{
    __shared__ float w_s[DEG][C];   // 16 KB: w[j][c], identical for all nodes

    const int tid = threadIdx.x;

    // ---- Precompute piecewise-linear weights w[j][c] once per block ----
    for (int p = tid; p < DEG * C; p += 256) {
        int j = p >> 7;
        int c = p & (C - 1);
        float t = (float)j / 31.0f;                 // n==32 for every node
        float index = (float)NPIECES * fminf(t, 1.0f);
        float fidx = floorf(index);
        int idx = (int)fidx;
        float frac = index - fidx;
        int idx2 = (idx + 1 > NPIECES) ? NPIECES : (idx + 1);
        float wv = (1.0f - frac) * weight[c * (NPIECES + 1) + idx]
                 + frac         * weight[c * (NPIECES + 1) + idx2];
        w_s[j][c] = wv;
    }
    __syncthreads();                // w_s ready; loop below is barrier-free

    const int c2 = tid & 63;        // channel pair: channels 2*c2, 2*c2+1
    const int wave = blockIdx.x * 4 + (tid >> 6);   // global wave id
    const float2* xp = (const float2*)x;

    for (int node = wave; node < N; node += nwaves) {
        // ---- wave-uniform node -> scalar col loads (s_load, SGPR bases) ----
        const int nu = __builtin_amdgcn_readfirstlane(node);
        const int* cb = col + nu * DEG;
        LDIDX(0)  LDIDX(1)  LDIDX(2)  LDIDX(3)  LDIDX(4)  LDIDX(5)  LDIDX(6)  LDIDX(7)
        LDIDX(8)  LDIDX(9)  LDIDX(10) LDIDX(11) LDIDX(12) LDIDX(13) LDIDX(14) LDIDX(15)
        LDIDX(16) LDIDX(17) LDIDX(18) LDIDX(19) LDIDX(20) LDIDX(21) LDIDX(22) LDIDX(23)
        LDIDX(24) LDIDX(25) LDIDX(26) LDIDX(27) LDIDX(28) LDIDX(29) LDIDX(30) LDIDX(31)

        // ---- gather 32 rows (SGPR base + shared voffset), pack f16, pin ----
        if constexpr (F16) {
            GATH16(0)  GATH16(1)  GATH16(2)  GATH16(3)
            GATH16(4)  GATH16(5)  GATH16(6)  GATH16(7)
            GATH16(8)  GATH16(9)  GATH16(10) GATH16(11)
            GATH16(12) GATH16(13) GATH16(14) GATH16(15)
            GATH16(16) GATH16(17) GATH16(18) GATH16(19)
            GATH16(20) GATH16(21) GATH16(22) GATH16(23)
            GATH16(24) GATH16(25) GATH16(26) GATH16(27)
            GATH16(28) GATH16(29) GATH16(30) GATH16(31)

            SORT_NET

            float acc0 = 0.0f, acc1 = 0.0f;
            ACC(0)  ACC(1)  ACC(2)  ACC(3)  ACC(4)  ACC(5)  ACC(6)  ACC(7)
            ACC(8)  ACC(9)  ACC(10) ACC(11) ACC(12) ACC(13) ACC(14) ACC(15)
            ACC(16) ACC(17) ACC(18) ACC(19) ACC(20) ACC(21) ACC(22) ACC(23)
            ACC(24) ACC(25) ACC(26) ACC(27) ACC(28) ACC(29) ACC(30) ACC(31)
            *(float2*)(out + node * C + 2 * c2) = make_float2(acc0, acc1);
        } else {
            GATH32(0)  GATH32(1)  GATH32(2)  GATH32(3)
            GATH32(4)  GATH32(5)  GATH32(6)  GATH32(7)
            GATH32(8)  GATH32(9)  GATH32(10) GATH32(11)
            GATH32(12) GATH32(13) GATH32(14) GATH32(15)
            GATH32(16) GATH32(17) GATH32(18) GATH32(19)
            GATH32(20) GATH32(21) GATH32(22) GATH32(23)
            GATH32(24) GATH32(25) GATH32(26) GATH32(27)
            GATH32(28) GATH32(29) GATH32(30) GATH32(31)

            SORT_NET

            float acc0 = 0.0f, acc1 = 0.0f;
            ACC(0)  ACC(1)  ACC(2)  ACC(3)  ACC(4)  ACC(5)  ACC(6)  ACC(7)
            ACC(8)  ACC(9)  ACC(10) ACC(11) ACC(12) ACC(13) ACC(14) ACC(15)
            ACC(16) ACC(17) ACC(18) ACC(19) ACC(20) ACC(21) ACC(22) ACC(23)
            ACC(24) ACC(25) ACC(26) ACC(27) ACC(28) ACC(29) ACC(30) ACC(31)
            *(float2*)(out + node * C + 2 * c2) = make_float2(acc0, acc1);
        }
    }
}

extern "C" void kernel_launch(void* const* d_in, const int* in_sizes, int n_in,
                              void* d_out, int out_size, void* d_ws, size_t ws_size,
                              hipStream_t stream) {
    const float* x      = (const float*)d_in[0];
    const int*   edge   = (const int*)d_in[1];
    const float* weight = (const float*)d_in[2];
    float*       out    = (float*)d_out;

    int N = in_sizes[0] / C;       // 20000
    int E = in_sizes[1] / 2;       // 640000
    const int* col = edge + E;     // edge_index[1]

    const int grid = 2048;         // 8 blocks/CU, 4 waves each
    const int nwaves = grid * 4;   // one node per wave, grid-stride

    const size_t need = (size_t)N * (C / 2) * sizeof(unsigned);  // 5.12 MB
    if (ws_size >= need) {
        unsigned* x16 = (unsigned*)d_ws;
        cvt_kernel<<<2048, 256, 0, stream>>>(x, x16, N * (C / 2));
        fspool_kernel<true><<<grid, 256, 0, stream>>>(x, x16, col, weight, out, N, nwaves);
    } else {
        fspool_kernel<false><<<grid, 256, 0, stream>>>(x, nullptr, col, weight, out, N, nwaves);
    }
}

// Round 8
// 63.752 us; speedup vs baseline: 1.2678x; 1.1267x over previous
//
#include <hip/hip_runtime.h>

#define C 128
#define DEG 32
#define NPIECES 5

typedef __fp16 h2 __attribute__((ext_vector_type(2)));

// Packed compare-and-swap: sorts both f16 lanes (2 channels) at once.
#define CD(a,b) { h2 _mx = __builtin_elementwise_max(v##a, v##b); \
                  v##b   = __builtin_elementwise_min(v##a, v##b); v##a = _mx; }
#define CA(a,b) { h2 _mn = __builtin_elementwise_min(v##a, v##b); \
                  v##b   = __builtin_elementwise_max(v##a, v##b); v##a = _mn; }

// Full 32-element descending bitonic network (240 comparators).
#define SORT_NET \
    CD(0,1) CA(2,3) CD(4,5) CA(6,7) CD(8,9) CA(10,11) CD(12,13) CA(14,15) \
    CD(16,17) CA(18,19) CD(20,21) CA(22,23) CD(24,25) CA(26,27) CD(28,29) CA(30,31) \
    CD(0,2) CD(1,3) CA(4,6) CA(5,7) CD(8,10) CD(9,11) CA(12,14) CA(13,15) \
    CD(16,18) CD(17,19) CA(20,22) CA(21,23) CD(24,26) CD(25,27) CA(28,30) CA(29,31) \
    CD(0,1) CD(2,3) CA(4,5) CA(6,7) CD(8,9) CD(10,11) CA(12,13) CA(14,15) \
    CD(16,17) CD(18,19) CA(20,21) CA(22,23) CD(24,25) CD(26,27) CA(28,29) CA(30,31) \
    CD(0,4) CD(1,5) CD(2,6) CD(3,7) CA(8,12) CA(9,13) CA(10,14) CA(11,15) \
    CD(16,20) CD(17,21) CD(18,22) CD(19,23) CA(24,28) CA(25,29) CA(26,30) CA(27,31) \
    CD(0,2) CD(1,3) CD(4,6) CD(5,7) CA(8,10) CA(9,11) CA(12,14) CA(13,15) \
    CD(16,18) CD(17,19) CD(20,22) CD(21,23) CA(24,26) CA(25,27) CA(28,30) CA(29,31) \
    CD(0,1) CD(2,3) CD(4,5) CD(6,7) CA(8,9) CA(10,11) CA(12,13) CA(14,15) \
    CD(16,17) CD(18,19) CD(20,21) CD(22,23) CA(24,25) CA(26,27) CA(28,29) CA(30,31) \
    CD(0,8) CD(1,9) CD(2,10) CD(3,11) CD(4,12) CD(5,13) CD(6,14) CD(7,15) \
    CA(16,24) CA(17,25) CA(18,26) CA(19,27) CA(20,28) CA(21,29) CA(22,30) CA(23,31) \
    CD(0,4) CD(1,5) CD(2,6) CD(3,7) CD(8,12) CD(9,13) CD(10,14) CD(11,15) \
    CA(16,20) CA(17,21) CA(18,22) CA(19,23) CA(24,28) CA(25,29) CA(26,30) CA(27,31) \
    CD(0,2) CD(1,3) CD(4,6) CD(5,7) CD(8,10) CD(9,11) CD(12,14) CD(13,15) \
    CA(16,18) CA(17,19) CA(20,22) CA(21,23) CA(24,26) CA(25,27) CA(28,30) CA(29,31) \
    CD(0,1) CD(2,3) CD(4,5) CD(6,7) CD(8,9) CD(10,11) CD(12,13) CD(14,15) \
    CA(16,17) CA(18,19) CA(20,21) CA(22,23) CA(24,25) CA(26,27) CA(28,29) CA(30,31) \
    CD(0,16) CD(1,17) CD(2,18) CD(3,19) CD(4,20) CD(5,21) CD(6,22) CD(7,23) \
    CD(8,24) CD(9,25) CD(10,26) CD(11,27) CD(12,28) CD(13,29) CD(14,30) CD(15,31) \
    CD(0,8) CD(1,9) CD(2,10) CD(3,11) CD(4,12) CD(5,13) CD(6,14) CD(7,15) \
    CD(16,24) CD(17,25) CD(18,26) CD(19,27) CD(20,28) CD(21,29) CD(22,30) CD(23,31) \
    CD(0,4) CD(1,5) CD(2,6) CD(3,7) CD(8,12) CD(9,13) CD(10,14) CD(11,15) \
    CD(16,20) CD(17,21) CD(18,22) CD(19,23) CD(24,28) CD(25,29) CD(26,30) CD(27,31) \
    CD(0,2) CD(1,3) CD(4,6) CD(5,7) CD(8,10) CD(9,11) CD(12,14) CD(13,15) \
    CD(16,18) CD(17,19) CD(20,22) CD(21,23) CD(24,26) CD(25,27) CD(28,30) CD(29,31) \
    CD(0,1) CD(2,3) CD(4,5) CD(6,7) CD(8,9) CD(10,11) CD(12,13) CD(14,15) \
    CD(16,17) CD(18,19) CD(20,21) CD(22,23) CD(24,25) CD(26,27) CD(28,29) CD(30,31)

#define REP32(M) M(0) M(1) M(2) M(3) M(4) M(5) M(6) M(7) M(8) M(9) M(10) M(11) \
    M(12) M(13) M(14) M(15) M(16) M(17) M(18) M(19) M(20) M(21) M(22) M(23) \
    M(24) M(25) M(26) M(27) M(28) M(29) M(30) M(31)

// Row index for gather i: pulled from lane (lane&32)+i via bpermute, so the
// lower/upper wave halves gather from their own node's neighbor rows.
#define GATH16(i) h2 v##i; { \
    int _ji = __builtin_amdgcn_ds_bpermute(lanesel + 4*(i), myrow); \
    unsigned _u = x16[(unsigned)(_ji + coff)]; \
    v##i = __builtin_bit_cast(h2, _u); \
    asm volatile("" : "+v"(v##i)); }

#define GATH32(i) h2 v##i; { \
    int _ji = __builtin_amdgcn_ds_bpermute(lanesel + 4*(i), myrow); \
    float2 _f = xp[(unsigned)(_ji + coff)]; \
    v##i = __builtin_amdgcn_cvt_pkrtz(_f.x, _f.y); \
    asm volatile("" : "+v"(v##i)); }

#define ACC(i) { float2 _w2 = *(const float2*)(&w_s[i][2 * c2l]); \
    acc0 = fmaf((float)v##i[0], _w2.x, acc0); \
    acc1 = fmaf((float)v##i[1], _w2.y, acc1); }

// ---- prepass: x (f32) -> packed f16x2 copy in workspace ----
__global__ __launch_bounds__(256) void cvt_kernel(
    const float* __restrict__ x, unsigned* __restrict__ x16, int total)
{
    for (int i = blockIdx.x * 256 + threadIdx.x; i < total; i += gridDim.x * 256) {
        float2 f = ((const float2*)x)[i];
        h2 h = __builtin_amdgcn_cvt_pkrtz(f.x, f.y);
        x16[i] = __builtin_bit_cast(unsigned, h);
    }
}

template <bool F16>
__global__ __launch_bounds__(256, 4) void fspool_kernel(
    const float* __restrict__ x,
    const unsigned* __restrict__ x16,
    const int* __restrict__ col,
    const float* __restrict__ weight,
    float* __restrict__ out,
    int N, int waves_per_group)
{
    // Channel group: even blocks -> XCDs 0,2,4,6 -> channels [0,64);
    // odd blocks -> XCDs 1,3,5,7 -> channels [64,128). Each XCD's L2 then
    // only caches half of x16 (2.56 MB < 4 MiB) -> gathers are L2 hits.
    const int g = blockIdx.x & 1;
    __shared__ float w_s[DEG][64];   // 8 KB: this group's w[j][c]

    const int tid = threadIdx.x;
    for (int p = tid; p < DEG * 64; p += 256) {
        int j = p >> 6;
        int cl = p & 63;
        int c = g * 64 + cl;
        float t = (float)j / 31.0f;                 // n==32 for every node
        float index = (float)NPIECES * fminf(t, 1.0f);
        float fidx = floorf(index);
        int idx = (int)fidx;
        float frac = index - fidx;
        int idx2 = (idx + 1 > NPIECES) ? NPIECES : (idx + 1);
        w_s[j][cl] = (1.0f - frac) * weight[c * (NPIECES + 1) + idx]
                   + frac         * weight[c * (NPIECES + 1) + idx2];
    }
    __syncthreads();                // w_s ready; loop below is barrier-free

    const int lane = tid & 63;
    const int c2l = lane & 31;               // channel pair within group
    const int lanesel = (lane & 32) << 2;    // bpermute src base per half
    const int coff = g * 32 + c2l;           // dword offset within a row
    const int wig = (blockIdx.x >> 1) * 4 + (tid >> 6);  // wave idx in group
    const int npairs = (N + 1) >> 1;
    const int E = N * DEG;
    const float2* xp = (const float2*)x;

    // Two nodes per wave: lanes 0-31 -> node 2p, lanes 32-63 -> node 2p+1.
    for (int p = wig; p < npairs; p += waves_per_group) {
        const int n0 = 2 * p;
        int ce = n0 * DEG + lane;            // 64 consecutive col entries
        int myrow = col[ce < E ? ce : 0] * (C / 2);

        if constexpr (F16) {
            REP32(GATH16)
            SORT_NET
            float acc0 = 0.0f, acc1 = 0.0f;
            REP32(ACC)
            int node = n0 + (lane >> 5);
            if (node < N)
                *(float2*)(out + node * C + g * 64 + 2 * c2l) = make_float2(acc0, acc1);
        } else {
            REP32(GATH32)
            SORT_NET
            float acc0 = 0.0f, acc1 = 0.0f;
            REP32(ACC)
            int node = n0 + (lane >> 5);
            if (node < N)
                *(float2*)(out + node * C + g * 64 + 2 * c2l) = make_float2(acc0, acc1);
        }
    }
}

extern "C" void kernel_launch(void* const* d_in, const int* in_sizes, int n_in,
                              void* d_out, int out_size, void* d_ws, size_t ws_size,
                              hipStream_t stream) {
    const float* x      = (const float*)d_in[0];
    const int*   edge   = (const int*)d_in[1];
    const float* weight = (const float*)d_in[2];
    float*       out    = (float*)d_out;

    int N = in_sizes[0] / C;       // 20000
    int E = in_sizes[1] / 2;       // 640000
    const int* col = edge + E;     // edge_index[1]

    // grid 1696 (multiple of 8): 848 blocks/group, 3392 waves/group,
    // 10000 pairs -> every wave does exactly 3 iterations (no tail imbalance).
    const int grid = 1696;
    const int wpg = (grid / 2) * 4;

    const size_t need = (size_t)N * (C / 2) * sizeof(unsigned);  // 5.12 MB
    if (ws_size >= need) {
        unsigned* x16 = (unsigned*)d_ws;
        cvt_kernel<<<2048, 256, 0, stream>>>(x, x16, N * (C / 2));
        fspool_kernel<true><<<grid, 256, 0, stream>>>(x, x16, col, weight, out, N, wpg);
    } else {
        fspool_kernel<false><<<grid, 256, 0, stream>>>(x, nullptr, col, weight, out, N, wpg);
    }
}

// Round 9
// 48.993 us; speedup vs baseline: 1.6497x; 1.3013x over previous
//
#include <hip/hip_runtime.h>

#define C 128
#define DEG 32
#define NPIECES 5

typedef __fp16 h2 __attribute__((ext_vector_type(2)));

// Packed compare-and-swap: sorts both f16 lanes (2 channels) at once.
#define CD(a,b) { h2 _mx = __builtin_elementwise_max(v##a, v##b); \
                  v##b   = __builtin_elementwise_min(v##a, v##b); v##a = _mx; }
#define CA(a,b) { h2 _mn = __builtin_elementwise_min(v##a, v##b); \
                  v##b   = __builtin_elementwise_max(v##a, v##b); v##a = _mn; }

// Full 32-element descending bitonic network (240 comparators).
#define SORT_NET \
    CD(0,1) CA(2,3) CD(4,5) CA(6,7) CD(8,9) CA(10,11) CD(12,13) CA(14,15) \
    CD(16,17) CA(18,19) CD(20,21) CA(22,23) CD(24,25) CA(26,27) CD(28,29) CA(30,31) \
    CD(0,2) CD(1,3) CA(4,6) CA(5,7) CD(8,10) CD(9,11) CA(12,14) CA(13,15) \
    CD(16,18) CD(17,19) CA(20,22) CA(21,23) CD(24,26) CD(25,27) CA(28,30) CA(29,31) \
    CD(0,1) CD(2,3) CA(4,5) CA(6,7) CD(8,9) CD(10,11) CA(12,13) CA(14,15) \
    CD(16,17) CD(18,19) CA(20,21) CA(22,23) CD(24,25) CD(26,27) CA(28,29) CA(30,31) \
    CD(0,4) CD(1,5) CD(2,6) CD(3,7) CA(8,12) CA(9,13) CA(10,14) CA(11,15) \
    CD(16,20) CD(17,21) CD(18,22) CD(19,23) CA(24,28) CA(25,29) CA(26,30) CA(27,31) \
    CD(0,2) CD(1,3) CD(4,6) CD(5,7) CA(8,10) CA(9,11) CA(12,14) CA(13,15) \
    CD(16,18) CD(17,19) CD(20,22) CD(21,23) CA(24,26) CA(25,27) CA(28,30) CA(29,31) \
    CD(0,1) CD(2,3) CD(4,5) CD(6,7) CA(8,9) CA(10,11) CA(12,13) CA(14,15) \
    CD(16,17) CD(18,19) CD(20,21) CD(22,23) CA(24,25) CA(26,27) CA(28,29) CA(30,31) \
    CD(0,8) CD(1,9) CD(2,10) CD(3,11) CD(4,12) CD(5,13) CD(6,14) CD(7,15) \
    CA(16,24) CA(17,25) CA(18,26) CA(19,27) CA(20,28) CA(21,29) CA(22,30) CA(23,31) \
    CD(0,4) CD(1,5) CD(2,6) CD(3,7) CD(8,12) CD(9,13) CD(10,14) CD(11,15) \
    CA(16,20) CA(17,21) CA(18,22) CA(19,23) CA(24,28) CA(25,29) CA(26,30) CA(27,31) \
    CD(0,2) CD(1,3) CD(4,6) CD(5,7) CD(8,10) CD(9,11) CD(12,14) CD(13,15) \
    CA(16,18) CA(17,19) CA(20,22) CA(21,23) CA(24,26) CA(25,27) CA(28,30) CA(29,31) \
    CD(0,1) CD(2,3) CD(4,5) CD(6,7) CD(8,9) CD(10,11) CD(12,13) CD(14,15) \
    CA(16,17) CA(18,19) CA(20,21) CA(22,23) CA(24,25) CA(26,27) CA(28,29) CA(30,31) \
    CD(0,16) CD(1,17) CD(2,18) CD(3,19) CD(4,20) CD(5,21) CD(6,22) CD(7,23) \
    CD(8,24) CD(9,25) CD(10,26) CD(11,27) CD(12,28) CD(13,29) CD(14,30) CD(15,31) \
    CD(0,8) CD(1,9) CD(2,10) CD(3,11) CD(4,12) CD(5,13) CD(6,14) CD(7,15) \
    CD(16,24) CD(17,25) CD(18,26) CD(19,27) CD(20,28) CD(21,29) CD(22,30) CD(23,31) \
    CD(0,4) CD(1,5) CD(2,6) CD(3,7) CD(8,12) CD(9,13) CD(10,14) CD(11,15) \
    CD(16,20) CD(17,21) CD(18,22) CD(19,23) CD(24,28) CD(25,29) CD(26,30) CD(27,31) \
    CD(0,2) CD(1,3) CD(4,6) CD(5,7) CD(8,10) CD(9,11) CD(12,14) CD(13,15) \
    CD(16,18) CD(17,19) CD(20,22) CD(21,23) CD(24,26) CD(25,27) CD(28,30) CD(29,31) \
    CD(0,1) CD(2,3) CD(4,5) CD(6,7) CD(8,9) CD(10,11) CD(12,13) CD(14,15) \
    CD(16,17) CD(18,19) CD(20,21) CD(22,23) CD(24,25) CD(26,27) CD(28,29) CD(30,31)

#define REP32(M) M(0) M(1) M(2) M(3) M(4) M(5) M(6) M(7) M(8) M(9) M(10) M(11) \
    M(12) M(13) M(14) M(15) M(16) M(17) M(18) M(19) M(20) M(21) M(22) M(23) \
    M(24) M(25) M(26) M(27) M(28) M(29) M(30) M(31)

// Bulk pin AFTER all loads: forces all 32 values live in VGPRs at one point
// (prevents remat/re-gather) WITHOUT serializing load issue the way
// per-value asm volatile pins did (volatile asm = conservative sched barrier).
#define PIN_ALL \
    asm volatile("" : "+v"(v0),"+v"(v1),"+v"(v2),"+v"(v3),"+v"(v4),"+v"(v5), \
                      "+v"(v6),"+v"(v7),"+v"(v8),"+v"(v9),"+v"(v10),"+v"(v11), \
                      "+v"(v12),"+v"(v13),"+v"(v14),"+v"(v15)); \
    asm volatile("" : "+v"(v16),"+v"(v17),"+v"(v18),"+v"(v19),"+v"(v20), \
                      "+v"(v21),"+v"(v22),"+v"(v23),"+v"(v24),"+v"(v25), \
                      "+v"(v26),"+v"(v27),"+v"(v28),"+v"(v29),"+v"(v30),"+v"(v31));

// Row index for gather i: pulled from lane (lane&32)+i via bpermute, so the
// lower/upper wave halves gather from their own node's neighbor rows.
// NO per-value pin: all 32 loads go into flight together.
#define GATH16(i) h2 v##i; { \
    int _ji = __builtin_amdgcn_ds_bpermute(lanesel + 4*(i), myrow); \
    v##i = __builtin_bit_cast(h2, x16[(unsigned)(_ji + coff)]); }

#define GATH32(i) h2 v##i; { \
    int _ji = __builtin_amdgcn_ds_bpermute(lanesel + 4*(i), myrow); \
    float2 _f = xp[(unsigned)(_ji + coff)]; \
    v##i = __builtin_amdgcn_cvt_pkrtz(_f.x, _f.y); }

#define ACC(i) { float2 _w2 = *(const float2*)(&w_s[i][2 * c2l]); \
    acc0 = fmaf((float)v##i[0], _w2.x, acc0); \
    acc1 = fmaf((float)v##i[1], _w2.y, acc1); }

// ---- prepass: x (f32) -> packed f16x2 copy in workspace (float4 in) ----
__global__ __launch_bounds__(256) void cvt_kernel(
    const float* __restrict__ x, unsigned* __restrict__ x16, int total4)
{
    for (int i = blockIdx.x * 256 + threadIdx.x; i < total4; i += gridDim.x * 256) {
        float4 f = ((const float4*)x)[i];
        h2 a = __builtin_amdgcn_cvt_pkrtz(f.x, f.y);
        h2 b = __builtin_amdgcn_cvt_pkrtz(f.z, f.w);
        uint2 u = make_uint2(__builtin_bit_cast(unsigned, a),
                             __builtin_bit_cast(unsigned, b));
        ((uint2*)x16)[i] = u;
    }
}

template <bool F16>
__global__ __launch_bounds__(256, 4) void fspool_kernel(
    const float* __restrict__ x,
    const unsigned* __restrict__ x16,
    const int* __restrict__ col,
    const float* __restrict__ weight,
    float* __restrict__ out,
    int N, int waves_per_group)
{
    // Channel group: even blocks -> XCDs 0,2,4,6 -> channels [0,64);
    // odd blocks -> XCDs 1,3,5,7 -> channels [64,128). Each XCD's L2 then
    // only caches half of x16 (2.56 MB < 4 MiB) -> gathers are L2 hits.
    const int g = blockIdx.x & 1;
    __shared__ float w_s[DEG][64];   // 8 KB: this group's w[j][c]

    const int tid = threadIdx.x;
    for (int p = tid; p < DEG * 64; p += 256) {
        int j = p >> 6;
        int cl = p & 63;
        int c = g * 64 + cl;
        float t = (float)j / 31.0f;                 // n==32 for every node
        float index = (float)NPIECES * fminf(t, 1.0f);
        float fidx = floorf(index);
        int idx = (int)fidx;
        float frac = index - fidx;
        int idx2 = (idx + 1 > NPIECES) ? NPIECES : (idx + 1);
        w_s[j][cl] = (1.0f - frac) * weight[c * (NPIECES + 1) + idx]
                   + frac         * weight[c * (NPIECES + 1) + idx2];
    }
    __syncthreads();                // w_s ready; loop below is barrier-free

    const int lane = tid & 63;
    const int c2l = lane & 31;               // channel pair within group
    const int lanesel = (lane & 32) << 2;    // bpermute src base per half
    const int coff = g * 32 + c2l;           // dword offset within a row
    const int wig = (blockIdx.x >> 1) * 4 + (tid >> 6);  // wave idx in group
    const int npairs = (N + 1) >> 1;
    const int E = N * DEG;
    const float2* xp = (const float2*)x;

    // Two nodes per wave: lanes 0-31 -> node 2p, lanes 32-63 -> node 2p+1.
    for (int p = wig; p < npairs; p += waves_per_group) {
        const int n0 = 2 * p;
        int ce = n0 * DEG + lane;            // 64 consecutive col entries
        int myrow = col[ce < E ? ce : 0] * (C / 2);

        if constexpr (F16) {
            REP32(GATH16)
            PIN_ALL
            SORT_NET
            float acc0 = 0.0f, acc1 = 0.0f;
            REP32(ACC)
            int node = n0 + (lane >> 5);
            if (node < N)
                *(float2*)(out + node * C + g * 64 + 2 * c2l) = make_float2(acc0, acc1);
        } else {
            REP32(GATH32)
            PIN_ALL
            SORT_NET
            float acc0 = 0.0f, acc1 = 0.0f;
            REP32(ACC)
            int node = n0 + (lane >> 5);
            if (node < N)
                *(float2*)(out + node * C + g * 64 + 2 * c2l) = make_float2(acc0, acc1);
        }
    }
}

extern "C" void kernel_launch(void* const* d_in, const int* in_sizes, int n_in,
                              void* d_out, int out_size, void* d_ws, size_t ws_size,
                              hipStream_t stream) {
    const float* x      = (const float*)d_in[0];
    const int*   edge   = (const int*)d_in[1];
    const float* weight = (const float*)d_in[2];
    float*       out    = (float*)d_out;

    int N = in_sizes[0] / C;       // 20000
    int E = in_sizes[1] / 2;       // 640000
    const int* col = edge + E;     // edge_index[1]

    // grid 1696 (multiple of 8): 848 blocks/group, 3392 waves/group.
    const int grid = 1696;
    const int wpg = (grid / 2) * 4;

    const size_t need = (size_t)N * (C / 2) * sizeof(unsigned);  // 5.12 MB
    if (ws_size >= need) {
        unsigned* x16 = (unsigned*)d_ws;
        cvt_kernel<<<1024, 256, 0, stream>>>(x, x16, N * (C / 4));
        fspool_kernel<true><<<grid, 256, 0, stream>>>(x, x16, col, weight, out, N, wpg);
    } else {
        fspool_kernel<false><<<grid, 256, 0, stream>>>(x, nullptr, col, weight, out, N, wpg);
    }
}

// Round 10
// 47.836 us; speedup vs baseline: 1.6896x; 1.0242x over previous
//
#include <hip/hip_runtime.h>

#define C 128
#define DEG 32
#define NPIECES 5

typedef __fp16 h2 __attribute__((ext_vector_type(2)));

// Packed compare-and-swap on named set P: sorts both f16 lanes at once.
#define CD(P,i,j) { h2 _mx = __builtin_elementwise_max(P##i, P##j); \
                    P##j   = __builtin_elementwise_min(P##i, P##j); P##i = _mx; }
#define CA(P,i,j) { h2 _mn = __builtin_elementwise_min(P##i, P##j); \
                    P##j   = __builtin_elementwise_max(P##i, P##j); P##i = _mn; }

// Full 32-element descending bitonic network (240 comparators) on set P.
#define SORT_NET(P) \
 CD(P,0,1) CA(P,2,3) CD(P,4,5) CA(P,6,7) CD(P,8,9) CA(P,10,11) CD(P,12,13) CA(P,14,15) \
 CD(P,16,17) CA(P,18,19) CD(P,20,21) CA(P,22,23) CD(P,24,25) CA(P,26,27) CD(P,28,29) CA(P,30,31) \
 CD(P,0,2) CD(P,1,3) CA(P,4,6) CA(P,5,7) CD(P,8,10) CD(P,9,11) CA(P,12,14) CA(P,13,15) \
 CD(P,16,18) CD(P,17,19) CA(P,20,22) CA(P,21,23) CD(P,24,26) CD(P,25,27) CA(P,28,30) CA(P,29,31) \
 CD(P,0,1) CD(P,2,3) CA(P,4,5) CA(P,6,7) CD(P,8,9) CD(P,10,11) CA(P,12,13) CA(P,14,15) \
 CD(P,16,17) CD(P,18,19) CA(P,20,21) CA(P,22,23) CD(P,24,25) CD(P,26,27) CA(P,28,29) CA(P,30,31) \
 CD(P,0,4) CD(P,1,5) CD(P,2,6) CD(P,3,7) CA(P,8,12) CA(P,9,13) CA(P,10,14) CA(P,11,15) \
 CD(P,16,20) CD(P,17,21) CD(P,18,22) CD(P,19,23) CA(P,24,28) CA(P,25,29) CA(P,26,30) CA(P,27,31) \
 CD(P,0,2) CD(P,1,3) CD(P,4,6) CD(P,5,7) CA(P,8,10) CA(P,9,11) CA(P,12,14) CA(P,13,15) \
 CD(P,16,18) CD(P,17,19) CD(P,20,22) CD(P,21,23) CA(P,24,26) CA(P,25,27) CA(P,28,30) CA(P,29,31) \
 CD(P,0,1) CD(P,2,3) CD(P,4,5) CD(P,6,7) CA(P,8,9) CA(P,10,11) CA(P,12,13) CA(P,14,15) \
 CD(P,16,17) CD(P,18,19) CD(P,20,21) CD(P,22,23) CA(P,24,25) CA(P,26,27) CA(P,28,29) CA(P,30,31) \
 CD(P,0,8) CD(P,1,9) CD(P,2,10) CD(P,3,11) CD(P,4,12) CD(P,5,13) CD(P,6,14) CD(P,7,15) \
 CA(P,16,24) CA(P,17,25) CA(P,18,26) CA(P,19,27) CA(P,20,28) CA(P,21,29) CA(P,22,30) CA(P,23,31) \
 CD(P,0,4) CD(P,1,5) CD(P,2,6) CD(P,3,7) CD(P,8,12) CD(P,9,13) CD(P,10,14) CD(P,11,15) \
 CA(P,16,20) CA(P,17,21) CA(P,18,22) CA(P,19,23) CA(P,24,28) CA(P,25,29) CA(P,26,30) CA(P,27,31) \
 CD(P,0,2) CD(P,1,3) CD(P,4,6) CD(P,5,7) CD(P,8,10) CD(P,9,11) CD(P,12,14) CD(P,13,15) \
 CA(P,16,18) CA(P,17,19) CA(P,20,22) CA(P,21,23) CA(P,24,26) CA(P,25,27) CA(P,28,30) CA(P,29,31) \
 CD(P,0,1) CD(P,2,3) CD(P,4,5) CD(P,6,7) CD(P,8,9) CD(P,10,11) CD(P,12,13) CD(P,14,15) \
 CA(P,16,17) CA(P,18,19) CA(P,20,21) CA(P,22,23) CA(P,24,25) CA(P,26,27) CA(P,28,29) CA(P,30,31) \
 CD(P,0,16) CD(P,1,17) CD(P,2,18) CD(P,3,19) CD(P,4,20) CD(P,5,21) CD(P,6,22) CD(P,7,23) \
 CD(P,8,24) CD(P,9,25) CD(P,10,26) CD(P,11,27) CD(P,12,28) CD(P,13,29) CD(P,14,30) CD(P,15,31) \
 CD(P,0,8) CD(P,1,9) CD(P,2,10) CD(P,3,11) CD(P,4,12) CD(P,5,13) CD(P,6,14) CD(P,7,15) \
 CD(P,16,24) CD(P,17,25) CD(P,18,26) CD(P,19,27) CD(P,20,28) CD(P,21,29) CD(P,22,30) CD(P,23,31) \
 CD(P,0,4) CD(P,1,5) CD(P,2,6) CD(P,3,7) CD(P,8,12) CD(P,9,13) CD(P,10,14) CD(P,11,15) \
 CD(P,16,20) CD(P,17,21) CD(P,18,22) CD(P,19,23) CD(P,24,28) CD(P,25,29) CD(P,26,30) CD(P,27,31) \
 CD(P,0,2) CD(P,1,3) CD(P,4,6) CD(P,5,7) CD(P,8,10) CD(P,9,11) CD(P,12,14) CD(P,13,15) \
 CD(P,16,18) CD(P,17,19) CD(P,20,22) CD(P,21,23) CD(P,24,26) CD(P,25,27) CD(P,28,30) CD(P,29,31) \
 CD(P,0,1) CD(P,2,3) CD(P,4,5) CD(P,6,7) CD(P,8,9) CD(P,10,11) CD(P,12,13) CD(P,14,15) \
 CD(P,16,17) CD(P,18,19) CD(P,20,21) CD(P,22,23) CD(P,24,25) CD(P,26,27) CD(P,28,29) CD(P,30,31)

#define REP32(M,P,X) M(P,0,X) M(P,1,X) M(P,2,X) M(P,3,X) M(P,4,X) M(P,5,X) M(P,6,X) M(P,7,X) \
 M(P,8,X) M(P,9,X) M(P,10,X) M(P,11,X) M(P,12,X) M(P,13,X) M(P,14,X) M(P,15,X) \
 M(P,16,X) M(P,17,X) M(P,18,X) M(P,19,X) M(P,20,X) M(P,21,X) M(P,22,X) M(P,23,X) \
 M(P,24,X) M(P,25,X) M(P,26,X) M(P,27,X) M(P,28,X) M(P,29,X) M(P,30,X) M(P,31,X)

#define DECL(P,i,X) h2 P##i;

// NON-volatile bulk pin: data-dependency-only. Forces all 32 values live in
// VGPRs at this point (blocks remat/re-gather) but lets the scheduler move
// unrelated loads (next stage's gathers) across it.
#define PIN_ALL(P) \
    asm("" : "+v"(P##0),"+v"(P##1),"+v"(P##2),"+v"(P##3),"+v"(P##4),"+v"(P##5), \
             "+v"(P##6),"+v"(P##7),"+v"(P##8),"+v"(P##9),"+v"(P##10),"+v"(P##11), \
             "+v"(P##12),"+v"(P##13),"+v"(P##14),"+v"(P##15)); \
    asm("" : "+v"(P##16),"+v"(P##17),"+v"(P##18),"+v"(P##19),"+v"(P##20), \
             "+v"(P##21),"+v"(P##22),"+v"(P##23),"+v"(P##24),"+v"(P##25), \
             "+v"(P##26),"+v"(P##27),"+v"(P##28),"+v"(P##29),"+v"(P##30),"+v"(P##31));

// Gather i: row byte-base pulled from lane (lane&32)+i via bpermute; one
// v_add (pre-scaled offsets) + global_load_dword per gather.
#define GATH16(P,i,MR) { \
    int _ji = __builtin_amdgcn_ds_bpermute(lanesel + 4*(i), MR); \
    P##i = __builtin_bit_cast(h2, *(const unsigned*)((const char*)x16 + (unsigned)(_ji + coff4))); }

#define GATH32(P,i,MR) { \
    int _ji = __builtin_amdgcn_ds_bpermute(lanesel + 4*(i), MR); \
    float2 _f = *(const float2*)((const char*)xp + (unsigned)(_ji + coff8)); \
    P##i = __builtin_amdgcn_cvt_pkrtz(_f.x, _f.y); }

// Packed-f16 multiply-accumulate against LDS weights (v_pk_fma_f16).
#define ACCM(P,i,X) _acc += P##i * wh[i][c2l];

#define LOAD_STAGE(P, PAIR) { \
    int _ce = 2*(PAIR)*DEG + lane; \
    _ce = _ce < E ? _ce : 0; \
    int _mr = col[_ce] << 8;            /* byte offset into x16: row*256 */ \
    if constexpr (F16) { REP32(GATH16,P,_mr) } \
    else { int _mr32 = _mr << 1; REP32(GATH32,P,_mr32) } }

#define PROC_STAGE(P, PAIR) { \
    PIN_ALL(P) \
    SORT_NET(P) \
    h2 _acc; _acc[0] = (__fp16)0.f; _acc[1] = (__fp16)0.f; \
    REP32(ACCM,P,0) \
    int _node = 2*(PAIR) + (lane >> 5); \
    if (_node < N) \
        *(float2*)(out + _node * C + g * 64 + 2 * c2l) = \
            make_float2((float)_acc[0], (float)_acc[1]); }

// ---- prepass: x (f32) -> packed f16x2 copy in workspace (float4 in) ----
__global__ __launch_bounds__(256) void cvt_kernel(
    const float* __restrict__ x, unsigned* __restrict__ x16, int total4)
{
    for (int i = blockIdx.x * 256 + threadIdx.x; i < total4; i += gridDim.x * 256) {
        float4 f = ((const float4*)x)[i];
        h2 a = __builtin_amdgcn_cvt_pkrtz(f.x, f.y);
        h2 b = __builtin_amdgcn_cvt_pkrtz(f.z, f.w);
        ((uint2*)x16)[i] = make_uint2(__builtin_bit_cast(unsigned, a),
                                      __builtin_bit_cast(unsigned, b));
    }
}

template <bool F16>
__global__ __launch_bounds__(256, 3) void fspool_kernel(
    const float* __restrict__ x,
    const unsigned* __restrict__ x16,
    const int* __restrict__ col,
    const float* __restrict__ weight,
    float* __restrict__ out,
    int N, int wpg)
{
    // Channel split: even blocks (XCDs 0,2,4,6) do channels [0,64), odd
    // blocks do [64,128) -> each XCD's L2 caches only 2.56 MB of x16.
    const int g = blockIdx.x & 1;
    __shared__ h2 wh[DEG][32];       // 4 KB: packed w[j][channel-pair]

    const int tid = threadIdx.x;
    for (int q = tid; q < DEG * 32; q += 256) {
        int j = q >> 5, cp = q & 31;
        int c0 = g * 64 + 2 * cp;
        float t = (float)j / 31.0f;                 // n==32 for every node
        float index = (float)NPIECES * fminf(t, 1.0f);
        float fidx = floorf(index);
        int idx = (int)fidx;
        float frac = index - fidx;
        int idx2 = (idx + 1 > NPIECES) ? NPIECES : (idx + 1);
        float w0 = (1.0f - frac) * weight[c0 * (NPIECES + 1) + idx]
                 + frac         * weight[c0 * (NPIECES + 1) + idx2];
        float w1 = (1.0f - frac) * weight[(c0 + 1) * (NPIECES + 1) + idx]
                 + frac         * weight[(c0 + 1) * (NPIECES + 1) + idx2];
        wh[j][cp] = __builtin_amdgcn_cvt_pkrtz(w0, w1);
    }
    __syncthreads();                 // wh ready; rest is barrier-free

    const int lane = tid & 63;
    const int c2l = lane & 31;               // channel pair within group
    const int lanesel = (lane & 32) << 2;    // bpermute src base per half
    const int coff4 = (g * 32 + c2l) * 4;    // byte offset within x16 row
    const int coff8 = (g * 32 + c2l) * 8;    // byte offset within x row
    const int wig = (blockIdx.x >> 1) * 4 + (tid >> 6);  // wave idx in group
    const int npairs = (N + 1) >> 1;
    const int E = N * DEG;
    const float2* xp = (const float2*)x;

    // 2-deep software pipeline over this wave's (up to) 3 pairs:
    // gathers for the next pair are in flight while the current pair sorts.
    const int p0 = wig, p1 = wig + wpg, p2 = wig + 2 * wpg;
    const bool q0 = p0 < npairs, q1 = p1 < npairs, q2 = p2 < npairs;

    REP32(DECL,a,0)
    REP32(DECL,b,0)

    if (q0) LOAD_STAGE(a, p0)
    if (q1) LOAD_STAGE(b, p1)
    if (q0) PROC_STAGE(a, p0)
    if (q2) LOAD_STAGE(a, p2)
    if (q1) PROC_STAGE(b, p1)
    if (q2) PROC_STAGE(a, p2)
}

extern "C" void kernel_launch(void* const* d_in, const int* in_sizes, int n_in,
                              void* d_out, int out_size, void* d_ws, size_t ws_size,
                              hipStream_t stream) {
    const float* x      = (const float*)d_in[0];
    const int*   edge   = (const int*)d_in[1];
    const float* weight = (const float*)d_in[2];
    float*       out    = (float*)d_out;

    int N = in_sizes[0] / C;       // 20000
    int E = in_sizes[1] / 2;       // 640000
    const int* col = edge + E;     // edge_index[1]

    // Size grid so each wave handles <= 3 pairs (pipeline depth).
    int npairs = (N + 1) >> 1;
    int wpg_needed = (npairs + 2) / 3;
    int bpg = (wpg_needed + 3) / 4;          // blocks per channel group
    int wpg = bpg * 4;                        // waves per group
    int grid = 2 * bpg;                       // npairs=10000 -> grid 1668

    const size_t need = (size_t)N * (C / 2) * sizeof(unsigned);  // 5.12 MB
    if (ws_size >= need) {
        unsigned* x16 = (unsigned*)d_ws;
        cvt_kernel<<<1024, 256, 0, stream>>>(x, x16, N * (C / 4));
        fspool_kernel<true><<<grid, 256, 0, stream>>>(x, x16, col, weight, out, N, wpg);
    } else {
        fspool_kernel<false><<<grid, 256, 0, stream>>>(x, nullptr, col, weight, out, N, wpg);
    }
}

// Round 13
// 46.922 us; speedup vs baseline: 1.7225x; 1.0195x over previous
//
#include <hip/hip_runtime.h>

#define C 128
#define DEG 32
#define NPIECES 5

typedef __fp16 h2 __attribute__((ext_vector_type(2)));

// Packed compare-and-swap on named set P: sorts both f16 lanes at once.
#define CD(P,i,j) { h2 _mx = __builtin_elementwise_max(P##i, P##j); \
                    P##j   = __builtin_elementwise_min(P##i, P##j); P##i = _mx; }
#define CA(P,i,j) { h2 _mn = __builtin_elementwise_min(P##i, P##j); \
                    P##j   = __builtin_elementwise_max(P##i, P##j); P##i = _mn; }

// Full 32-element descending bitonic network (240 comparators) on set P.
#define SORT_NET(P) \
 CD(P,0,1) CA(P,2,3) CD(P,4,5) CA(P,6,7) CD(P,8,9) CA(P,10,11) CD(P,12,13) CA(P,14,15) \
 CD(P,16,17) CA(P,18,19) CD(P,20,21) CA(P,22,23) CD(P,24,25) CA(P,26,27) CD(P,28,29) CA(P,30,31) \
 CD(P,0,2) CD(P,1,3) CA(P,4,6) CA(P,5,7) CD(P,8,10) CD(P,9,11) CA(P,12,14) CA(P,13,15) \
 CD(P,16,18) CD(P,17,19) CA(P,20,22) CA(P,21,23) CD(P,24,26) CD(P,25,27) CA(P,28,30) CA(P,29,31) \
 CD(P,0,1) CD(P,2,3) CA(P,4,5) CA(P,6,7) CD(P,8,9) CD(P,10,11) CA(P,12,13) CA(P,14,15) \
 CD(P,16,17) CD(P,18,19) CA(P,20,21) CA(P,22,23) CD(P,24,25) CD(P,26,27) CA(P,28,29) CA(P,30,31) \
 CD(P,0,4) CD(P,1,5) CD(P,2,6) CD(P,3,7) CA(P,8,12) CA(P,9,13) CA(P,10,14) CA(P,11,15) \
 CD(P,16,20) CD(P,17,21) CD(P,18,22) CD(P,19,23) CA(P,24,28) CA(P,25,29) CA(P,26,30) CA(P,27,31) \
 CD(P,0,2) CD(P,1,3) CD(P,4,6) CD(P,5,7) CA(P,8,10) CA(P,9,11) CA(P,12,14) CA(P,13,15) \
 CD(P,16,18) CD(P,17,19) CD(P,20,22) CD(P,21,23) CA(P,24,26) CA(P,25,27) CA(P,28,30) CA(P,29,31) \
 CD(P,0,1) CD(P,2,3) CD(P,4,5) CD(P,6,7) CA(P,8,9) CA(P,10,11) CA(P,12,13) CA(P,14,15) \
 CD(P,16,17) CD(P,18,19) CD(P,20,21) CD(P,22,23) CA(P,24,25) CA(P,26,27) CA(P,28,29) CA(P,30,31) \
 CD(P,0,8) CD(P,1,9) CD(P,2,10) CD(P,3,11) CD(P,4,12) CD(P,5,13) CD(P,6,14) CD(P,7,15) \
 CA(P,16,24) CA(P,17,25) CA(P,18,26) CA(P,19,27) CA(P,20,28) CA(P,21,29) CA(P,22,30) CA(P,23,31) \
 CD(P,0,4) CD(P,1,5) CD(P,2,6) CD(P,3,7) CD(P,8,12) CD(P,9,13) CD(P,10,14) CD(P,11,15) \
 CA(P,16,20) CA(P,17,21) CA(P,18,22) CA(P,19,23) CA(P,24,28) CA(P,25,29) CA(P,26,30) CA(P,27,31) \
 CD(P,0,2) CD(P,1,3) CD(P,4,6) CD(P,5,7) CD(P,8,10) CD(P,9,11) CD(P,12,14) CD(P,13,15) \
 CA(P,16,18) CA(P,17,19) CA(P,20,22) CA(P,21,23) CA(P,24,26) CA(P,25,27) CA(P,28,30) CA(P,29,31) \
 CD(P,0,1) CD(P,2,3) CD(P,4,5) CD(P,6,7) CD(P,8,9) CD(P,10,11) CD(P,12,13) CD(P,14,15) \
 CA(P,16,17) CA(P,18,19) CA(P,20,21) CA(P,22,23) CA(P,24,25) CA(P,26,27) CA(P,28,29) CA(P,30,31) \
 CD(P,0,16) CD(P,1,17) CD(P,2,18) CD(P,3,19) CD(P,4,20) CD(P,5,21) CD(P,6,22) CD(P,7,23) \
 CD(P,8,24) CD(P,9,25) CD(P,10,26) CD(P,11,27) CD(P,12,28) CD(P,13,29) CD(P,14,30) CD(P,15,31) \
 CD(P,0,8) CD(P,1,9) CD(P,2,10) CD(P,3,11) CD(P,4,12) CD(P,5,13) CD(P,6,14) CD(P,7,15) \
 CD(P,16,24) CD(P,17,25) CD(P,18,26) CD(P,19,27) CD(P,20,28) CD(P,21,29) CD(P,22,30) CD(P,23,31) \
 CD(P,0,4) CD(P,1,5) CD(P,2,6) CD(P,3,7) CD(P,8,12) CD(P,9,13) CD(P,10,14) CD(P,11,15) \
 CD(P,16,20) CD(P,17,21) CD(P,18,22) CD(P,19,23) CD(P,24,28) CD(P,25,29) CD(P,26,30) CD(P,27,31) \
 CD(P,0,2) CD(P,1,3) CD(P,4,6) CD(P,5,7) CD(P,8,10) CD(P,9,11) CD(P,12,14) CD(P,13,15) \
 CD(P,16,18) CD(P,17,19) CD(P,20,22) CD(P,21,23) CD(P,24,26) CD(P,25,27) CD(P,28,30) CD(P,29,31) \
 CD(P,0,1) CD(P,2,3) CD(P,4,5) CD(P,6,7) CD(P,8,9) CD(P,10,11) CD(P,12,13) CD(P,14,15) \
 CD(P,16,17) CD(P,18,19) CD(P,20,21) CD(P,22,23) CD(P,24,25) CD(P,26,27) CD(P,28,29) CD(P,30,31)

#define REP32(M,P) M(P,0) M(P,1) M(P,2) M(P,3) M(P,4) M(P,5) M(P,6) M(P,7) \
 M(P,8) M(P,9) M(P,10) M(P,11) M(P,12) M(P,13) M(P,14) M(P,15) \
 M(P,16) M(P,17) M(P,18) M(P,19) M(P,20) M(P,21) M(P,22) M(P,23) \
 M(P,24) M(P,25) M(P,26) M(P,27) M(P,28) M(P,29) M(P,30) M(P,31)

#define DECLV(P,i) h2 P##i;

// Non-volatile bulk pin: all 32 values live at this point (blocks remat /
// re-gather) without serializing load issue.
#define PIN_ALL(P) \
    asm("" : "+v"(P##0),"+v"(P##1),"+v"(P##2),"+v"(P##3),"+v"(P##4),"+v"(P##5), \
             "+v"(P##6),"+v"(P##7),"+v"(P##8),"+v"(P##9),"+v"(P##10),"+v"(P##11), \
             "+v"(P##12),"+v"(P##13),"+v"(P##14),"+v"(P##15)); \
    asm("" : "+v"(P##16),"+v"(P##17),"+v"(P##18),"+v"(P##19),"+v"(P##20), \
             "+v"(P##21),"+v"(P##22),"+v"(P##23),"+v"(P##24),"+v"(P##25), \
             "+v"(P##26),"+v"(P##27),"+v"(P##28),"+v"(P##29),"+v"(P##30),"+v"(P##31));

// Gather i: row DWORD-base from per-wave LDS table (padded: entry (q,i) at
// rows[wid][q*33+i] -> banks (q+i)%32 conflict-free; 16 lanes of a q-group
// read the same address = broadcast). ALL OFFSETS IN DWORDS (bug fix R12).
#define GATH16(P,i) { \
    int _rb = rw[qpad + (i)]; \
    P##i = __builtin_bit_cast(h2, x16g[(unsigned)_rb + c2l]); }

// f32 fallback: row base = _rb*8 floats (=col*128), channel pair = 2*c2l floats.
#define GATH32(P,i) { \
    int _rb = rw[qpad + (i)]; \
    float2 _f = *(const float2*)(xg + (unsigned)_rb * 8 + 2 * c2l); \
    P##i = __builtin_amdgcn_cvt_pkrtz(_f.x, _f.y); }

#define ACCM(P,i) _acc += P##i * wh[i][c2l];

// ---- prepass: x (f32) -> packed f16, GROUP-MAJOR layout ----
// x16[(g*N + node)*16 + cp] (dwords), g = c/32, cp = (c&31)/2.
// Per-XCD gather working set becomes 1.28 MB contiguous -> L2-resident.
__global__ __launch_bounds__(256) void cvt_kernel(
    const float* __restrict__ x, unsigned* __restrict__ x16, int total4, int N)
{
    for (int i = blockIdx.x * 256 + threadIdx.x; i < total4; i += gridDim.x * 256) {
        float4 f = ((const float4*)x)[i];           // node i>>5, channels (i&31)*4..+3
        int node = i >> 5;
        int g = (i & 31) >> 3;
        uint2 u = make_uint2(
            __builtin_bit_cast(unsigned, __builtin_amdgcn_cvt_pkrtz(f.x, f.y)),
            __builtin_bit_cast(unsigned, __builtin_amdgcn_cvt_pkrtz(f.z, f.w)));
        ((uint2*)x16)[(size_t)(g * N + node) * 8 + (i & 7)] = u;
    }
}

template <bool F16>
__global__ __launch_bounds__(256, 6) void fspool_kernel(
    const float* __restrict__ x,
    const unsigned* __restrict__ x16,
    const int* __restrict__ col,
    const float* __restrict__ weight,
    float* __restrict__ out,
    int N, int wpg)
{
    // 4-way channel split: g = blockIdx&3. Under round-robin dispatch
    // (XCD = blockIdx%8), each XCD runs exactly one g.
    const int g = blockIdx.x & 3;
    __shared__ h2 wh[DEG][16];       // 2 KB: packed w[j][channel-pair] for group
    __shared__ int rows[4][134];     // per-wave padded row-offset tables

    const int tid = threadIdx.x;
    for (int q = tid; q < DEG * 16; q += 256) {
        int j = q >> 4, cp = q & 15;
        int c0 = g * 32 + 2 * cp;
        float t = (float)j / 31.0f;                 // n==32 for every node
        float index = (float)NPIECES * fminf(t, 1.0f);
        float fidx = floorf(index);
        int idx = (int)fidx;
        float frac = index - fidx;
        int idx2 = (idx + 1 > NPIECES) ? NPIECES : (idx + 1);
        float w0 = (1.0f - frac) * weight[c0 * (NPIECES + 1) + idx]
                 + frac         * weight[c0 * (NPIECES + 1) + idx2];
        float w1 = (1.0f - frac) * weight[(c0 + 1) * (NPIECES + 1) + idx]
                 + frac         * weight[(c0 + 1) * (NPIECES + 1) + idx2];
        wh[j][cp] = __builtin_amdgcn_cvt_pkrtz(w0, w1);
    }
    __syncthreads();                 // wh ready; rest is barrier-free

    const int lane = tid & 63;
    const int wid  = tid >> 6;
    const int c2l  = lane & 15;                  // channel pair within group
    const int q    = lane >> 4;                  // node slot within quad (0..3)
    const int qpad = q * 33;                     // padded LDS row-table base
    int* rw = rows[wid];
    // write side of padded table: lane l holds entry l -> [l/32*33 + l%32]
    const int wpad0 = (lane >> 5) * 33 + (lane & 31);

    const int wig = (blockIdx.x >> 2) * 4 + wid; // wave index within group
    const int nquads = (N + 3) >> 2;
    const int E = N * DEG;
    // group-sliced bases
    const unsigned* x16g = x16 + (size_t)g * N * 16;   // f16: 16 dwords/node
    const float*    xg   = x + g * 32;                 // f32 fallback slice

    for (int quad = wig; quad < nquads; quad += wpg) {
        // 128 neighbor row offsets (in dwords: col*16) for this quad -> LDS.
        int ce0 = quad * 128 + lane;
        int ce1 = ce0 + 64;
        ce0 = ce0 < E ? ce0 : 0;
        ce1 = ce1 < E ? ce1 : 0;
        rw[wpad0]      = col[ce0] * 16;   // dword offset of row slice
        rw[66 + wpad0] = col[ce1] * 16;   // entries 64..127 -> q=2,3 (2*33=66)

        int node = quad * 4 + q;

        if constexpr (F16) {
            REP32(DECLV, v)
            REP32(GATH16, v)
            PIN_ALL(v)
            SORT_NET(v)
            h2 _acc; _acc[0] = (__fp16)0.f; _acc[1] = (__fp16)0.f;
            REP32(ACCM, v)
            if (node < N)
                *(float2*)(out + (size_t)node * C + g * 32 + 2 * c2l) =
                    make_float2((float)_acc[0], (float)_acc[1]);
        } else {
            REP32(DECLV, u)
            REP32(GATH32, u)
            PIN_ALL(u)
            SORT_NET(u)
            h2 _acc; _acc[0] = (__fp16)0.f; _acc[1] = (__fp16)0.f;
            REP32(ACCM, u)
            if (node < N)
                *(float2*)(out + (size_t)node * C + g * 32 + 2 * c2l) =
                    make_float2((float)_acc[0], (float)_acc[1]);
        }
    }
}

extern "C" void kernel_launch(void* const* d_in, const int* in_sizes, int n_in,
                              void* d_out, int out_size, void* d_ws, size_t ws_size,
                              hipStream_t stream) {
    const float* x      = (const float*)d_in[0];
    const int*   edge   = (const int*)d_in[1];
    const float* weight = (const float*)d_in[2];
    float*       out    = (float*)d_out;

    int N = in_sizes[0] / C;       // 20000
    int E = in_sizes[1] / 2;       // 640000
    const int* col = edge + E;     // edge_index[1]

    // grid multiple of 8 (XCD balance) and of 4 (group balance).
    // 1672 blocks -> 418/group -> 1672 waves/group; 5000 quads -> <=3 iters.
    const int grid = 1672;
    const int wpg  = grid;         // waves per group == stride

    const size_t need = (size_t)N * (C / 2) * sizeof(unsigned);  // 5.12 MB
    if (ws_size >= need) {
        unsigned* x16 = (unsigned*)d_ws;
        cvt_kernel<<<1024, 256, 0, stream>>>(x, x16, N * (C / 4), N);
        fspool_kernel<true><<<grid, 256, 0, stream>>>(x, x16, col, weight, out, N, wpg);
    } else {
        fspool_kernel<false><<<grid, 256, 0, stream>>>(x, nullptr, col, weight, out, N, wpg);
    }
}

// Round 14
// 42.343 us; speedup vs baseline: 1.9088x; 1.1081x over previous
//
#include <hip/hip_runtime.h>

#define C 128
#define DEG 32
#define NPIECES 5

typedef __fp16 h2 __attribute__((ext_vector_type(2)));

// Packed compare-and-swap on named set P: sorts both f16 lanes at once.
#define CD(P,i,j) { h2 _mx = __builtin_elementwise_max(P##i, P##j); \
                    P##j   = __builtin_elementwise_min(P##i, P##j); P##i = _mx; }
#define CA(P,i,j) { h2 _mn = __builtin_elementwise_min(P##i, P##j); \
                    P##j   = __builtin_elementwise_max(P##i, P##j); P##i = _mn; }

// Full 32-element descending bitonic network (240 comparators) on set P.
#define SORT_NET(P) \
 CD(P,0,1) CA(P,2,3) CD(P,4,5) CA(P,6,7) CD(P,8,9) CA(P,10,11) CD(P,12,13) CA(P,14,15) \
 CD(P,16,17) CA(P,18,19) CD(P,20,21) CA(P,22,23) CD(P,24,25) CA(P,26,27) CD(P,28,29) CA(P,30,31) \
 CD(P,0,2) CD(P,1,3) CA(P,4,6) CA(P,5,7) CD(P,8,10) CD(P,9,11) CA(P,12,14) CA(P,13,15) \
 CD(P,16,18) CD(P,17,19) CA(P,20,22) CA(P,21,23) CD(P,24,26) CD(P,25,27) CA(P,28,30) CA(P,29,31) \
 CD(P,0,1) CD(P,2,3) CA(P,4,5) CA(P,6,7) CD(P,8,9) CD(P,10,11) CA(P,12,13) CA(P,14,15) \
 CD(P,16,17) CD(P,18,19) CA(P,20,21) CA(P,22,23) CD(P,24,25) CD(P,26,27) CA(P,28,29) CA(P,30,31) \
 CD(P,0,4) CD(P,1,5) CD(P,2,6) CD(P,3,7) CA(P,8,12) CA(P,9,13) CA(P,10,14) CA(P,11,15) \
 CD(P,16,20) CD(P,17,21) CD(P,18,22) CD(P,19,23) CA(P,24,28) CA(P,25,29) CA(P,26,30) CA(P,27,31) \
 CD(P,0,2) CD(P,1,3) CD(P,4,6) CD(P,5,7) CA(P,8,10) CA(P,9,11) CA(P,12,14) CA(P,13,15) \
 CD(P,16,18) CD(P,17,19) CD(P,20,22) CD(P,21,23) CA(P,24,26) CA(P,25,27) CA(P,28,30) CA(P,29,31) \
 CD(P,0,1) CD(P,2,3) CD(P,4,5) CD(P,6,7) CA(P,8,9) CA(P,10,11) CA(P,12,13) CA(P,14,15) \
 CD(P,16,17) CD(P,18,19) CD(P,20,21) CD(P,22,23) CA(P,24,25) CA(P,26,27) CA(P,28,29) CA(P,30,31) \
 CD(P,0,8) CD(P,1,9) CD(P,2,10) CD(P,3,11) CD(P,4,12) CD(P,5,13) CD(P,6,14) CD(P,7,15) \
 CA(P,16,24) CA(P,17,25) CA(P,18,26) CA(P,19,27) CA(P,20,28) CA(P,21,29) CA(P,22,30) CA(P,23,31) \
 CD(P,0,4) CD(P,1,5) CD(P,2,6) CD(P,3,7) CD(P,8,12) CD(P,9,13) CD(P,10,14) CD(P,11,15) \
 CA(P,16,20) CA(P,17,21) CA(P,18,22) CA(P,19,23) CA(P,24,28) CA(P,25,29) CA(P,26,30) CA(P,27,31) \
 CD(P,0,2) CD(P,1,3) CD(P,4,6) CD(P,5,7) CD(P,8,10) CD(P,9,11) CD(P,12,14) CD(P,13,15) \
 CA(P,16,18) CA(P,17,19) CA(P,20,22) CA(P,21,23) CA(P,24,26) CA(P,25,27) CA(P,28,30) CA(P,29,31) \
 CD(P,0,1) CD(P,2,3) CD(P,4,5) CD(P,6,7) CD(P,8,9) CD(P,10,11) CD(P,12,13) CD(P,14,15) \
 CA(P,16,17) CA(P,18,19) CA(P,20,21) CA(P,22,23) CA(P,24,25) CA(P,26,27) CA(P,28,29) CA(P,30,31) \
 CD(P,0,16) CD(P,1,17) CD(P,2,18) CD(P,3,19) CD(P,4,20) CD(P,5,21) CD(P,6,22) CD(P,7,23) \
 CD(P,8,24) CD(P,9,25) CD(P,10,26) CD(P,11,27) CD(P,12,28) CD(P,13,29) CD(P,14,30) CD(P,15,31) \
 CD(P,0,8) CD(P,1,9) CD(P,2,10) CD(P,3,11) CD(P,4,12) CD(P,5,13) CD(P,6,14) CD(P,7,15) \
 CD(P,16,24) CD(P,17,25) CD(P,18,26) CD(P,19,27) CD(P,20,28) CD(P,21,29) CD(P,22,30) CD(P,23,31) \
 CD(P,0,4) CD(P,1,5) CD(P,2,6) CD(P,3,7) CD(P,8,12) CD(P,9,13) CD(P,10,14) CD(P,11,15) \
 CD(P,16,20) CD(P,17,21) CD(P,18,22) CD(P,19,23) CD(P,24,28) CD(P,25,29) CD(P,26,30) CD(P,27,31) \
 CD(P,0,2) CD(P,1,3) CD(P,4,6) CD(P,5,7) CD(P,8,10) CD(P,9,11) CD(P,12,14) CD(P,13,15) \
 CD(P,16,18) CD(P,17,19) CD(P,20,22) CD(P,21,23) CD(P,24,26) CD(P,25,27) CD(P,28,30) CD(P,29,31) \
 CD(P,0,1) CD(P,2,3) CD(P,4,5) CD(P,6,7) CD(P,8,9) CD(P,10,11) CD(P,12,13) CD(P,14,15) \
 CD(P,16,17) CD(P,18,19) CD(P,20,21) CD(P,22,23) CD(P,24,25) CD(P,26,27) CD(P,28,29) CD(P,30,31)

#define REP32(M,P) M(P,0) M(P,1) M(P,2) M(P,3) M(P,4) M(P,5) M(P,6) M(P,7) \
 M(P,8) M(P,9) M(P,10) M(P,11) M(P,12) M(P,13) M(P,14) M(P,15) \
 M(P,16) M(P,17) M(P,18) M(P,19) M(P,20) M(P,21) M(P,22) M(P,23) \
 M(P,24) M(P,25) M(P,26) M(P,27) M(P,28) M(P,29) M(P,30) M(P,31)

#define DECLV(P,i) h2 P##i;

// Non-volatile bulk pin: all 32 values live at this point (blocks remat /
// re-gather) without serializing load issue.
#define PIN_ALL(P) \
    asm("" : "+v"(P##0),"+v"(P##1),"+v"(P##2),"+v"(P##3),"+v"(P##4),"+v"(P##5), \
             "+v"(P##6),"+v"(P##7),"+v"(P##8),"+v"(P##9),"+v"(P##10),"+v"(P##11), \
             "+v"(P##12),"+v"(P##13),"+v"(P##14),"+v"(P##15)); \
    asm("" : "+v"(P##16),"+v"(P##17),"+v"(P##18),"+v"(P##19),"+v"(P##20), \
             "+v"(P##21),"+v"(P##22),"+v"(P##23),"+v"(P##24),"+v"(P##25), \
             "+v"(P##26),"+v"(P##27),"+v"(P##28),"+v"(P##29),"+v"(P##30),"+v"(P##31));

// Gather i: row DWORD-base from per-wave LDS table (padded: entry (q,i) at
// rows[wid][q*33+i] -> 4 distinct banks, 16-lane broadcast, conflict-free).
#define GATH16(P,i) { \
    int _rb = rw[qpad + (i)]; \
    P##i = __builtin_bit_cast(h2, x16g[(unsigned)_rb + c2l]); }

// f32 fallback: row base = _rb*8 floats (=col*128), channel pair = 2*c2l.
#define GATH32(P,i) { \
    int _rb = rw[qpad + (i)]; \
    float2 _f = *(const float2*)(xg + (unsigned)_rb * 8 + 2 * c2l); \
    P##i = __builtin_amdgcn_cvt_pkrtz(_f.x, _f.y); }

#define ACCM(P,i) _acc += P##i * wh[i][c2l];

// ---- prepass: x (f32) -> packed f16, GROUP-MAJOR layout ----
// x16[(g*N + node)*16 + cp] (dwords), g = c/32, cp = (c&31)/2.
__global__ __launch_bounds__(256) void cvt_kernel(
    const float* __restrict__ x, unsigned* __restrict__ x16, int total4, int N)
{
    for (int i = blockIdx.x * 256 + threadIdx.x; i < total4; i += gridDim.x * 256) {
        float4 f = ((const float4*)x)[i];           // node i>>5, channels (i&31)*4..+3
        int node = i >> 5;
        int g = (i & 31) >> 3;
        uint2 u = make_uint2(
            __builtin_bit_cast(unsigned, __builtin_amdgcn_cvt_pkrtz(f.x, f.y)),
            __builtin_bit_cast(unsigned, __builtin_amdgcn_cvt_pkrtz(f.z, f.w)));
        ((uint2*)x16)[(size_t)(g * N + node) * 8 + (i & 7)] = u;
    }
}

template <bool F16>
__global__ __launch_bounds__(256, 6) void fspool_kernel(
    const float* __restrict__ x,
    const unsigned* __restrict__ x16,
    const int* __restrict__ col,
    const float* __restrict__ weight,
    float* __restrict__ out,
    int N, int wpg)
{
    // 4-way channel split: g = blockIdx&3 (XCD = blockIdx%8 round-robin ->
    // each XCD's L2 caches one 1.28 MB group slice of x16).
    const int g = blockIdx.x & 3;
    __shared__ h2 wh[DEG][16];       // 2 KB: packed w[j][channel-pair] for group
    __shared__ int rows[4][134];     // per-wave padded row-offset tables

    const int tid = threadIdx.x;
    for (int q = tid; q < DEG * 16; q += 256) {
        int j = q >> 4, cp = q & 15;
        int c0 = g * 32 + 2 * cp;
        float t = (float)j / 31.0f;                 // n==32 for every node
        float index = (float)NPIECES * fminf(t, 1.0f);
        float fidx = floorf(index);
        int idx = (int)fidx;
        float frac = index - fidx;
        int idx2 = (idx + 1 > NPIECES) ? NPIECES : (idx + 1);
        float w0 = (1.0f - frac) * weight[c0 * (NPIECES + 1) + idx]
                 + frac         * weight[c0 * (NPIECES + 1) + idx2];
        float w1 = (1.0f - frac) * weight[(c0 + 1) * (NPIECES + 1) + idx]
                 + frac         * weight[(c0 + 1) * (NPIECES + 1) + idx2];
        wh[j][cp] = __builtin_amdgcn_cvt_pkrtz(w0, w1);
    }
    __syncthreads();                 // wh ready; rest is barrier-free

    const int lane = tid & 63;
    const int wid  = tid >> 6;
    const int c2l  = lane & 15;                  // channel pair within group
    const int q    = lane >> 4;                  // node slot within quad (0..3)
    const int qpad = q * 33;                     // padded LDS row-table base
    int* rw = rows[wid];
    // write side of padded table: lane l holds entry l -> [l/32*33 + l%32]
    const int wpad0 = (lane >> 5) * 33 + (lane & 31);

    const int wig = (blockIdx.x >> 2) * 4 + wid; // wave index within group
    const int nquads = (N + 3) >> 2;
    // group-sliced bases
    const unsigned* x16g = x16 + (size_t)g * N * 16;   // f16: 16 dwords/node
    const float*    xg   = x + g * 32;                 // f32 fallback slice

    // ---- software-pipelined col loads: current quad's 2 entries live in
    // registers; next quad's load issues before the sort so its latency
    // hides under gathers+sort. Per-wave private LDS table -> no barriers.
    int quad = wig;
    int cr0, cr1;
    if (quad < nquads) {
        int ce = quad * 128 + lane;
        cr0 = col[ce];
        cr1 = col[ce + 64];
    }

    for (; quad < nquads; quad += wpg) {
        rw[wpad0]      = cr0 * 16;   // dword offset of row slice
        rw[66 + wpad0] = cr1 * 16;   // entries 64..127 -> q=2,3

        int nq = quad + wpg;         // prefetch next quad's col entries
        if (nq < nquads) {
            int ce = nq * 128 + lane;
            cr0 = col[ce];
            cr1 = col[ce + 64];
        }

        int node = quad * 4 + q;

        if constexpr (F16) {
            REP32(DECLV, v)
            REP32(GATH16, v)
            PIN_ALL(v)
            SORT_NET(v)
            h2 _acc; _acc[0] = (__fp16)0.f; _acc[1] = (__fp16)0.f;
            REP32(ACCM, v)
            if (node < N)
                *(float2*)(out + (size_t)node * C + g * 32 + 2 * c2l) =
                    make_float2((float)_acc[0], (float)_acc[1]);
        } else {
            REP32(DECLV, u)
            REP32(GATH32, u)
            PIN_ALL(u)
            SORT_NET(u)
            h2 _acc; _acc[0] = (__fp16)0.f; _acc[1] = (__fp16)0.f;
            REP32(ACCM, u)
            if (node < N)
                *(float2*)(out + (size_t)node * C + g * 32 + 2 * c2l) =
                    make_float2((float)_acc[0], (float)_acc[1]);
        }
    }
}

extern "C" void kernel_launch(void* const* d_in, const int* in_sizes, int n_in,
                              void* d_out, int out_size, void* d_ws, size_t ws_size,
                              hipStream_t stream) {
    const float* x      = (const float*)d_in[0];
    const int*   edge   = (const int*)d_in[1];
    const float* weight = (const float*)d_in[2];
    float*       out    = (float*)d_out;

    int N = in_sizes[0] / C;       // 20000
    int E = in_sizes[1] / 2;       // 640000
    const int* col = edge + E;     // edge_index[1]

    // grid 2504 (multiple of 8): 626 blocks/group, 2504 waves/group;
    // 5000 quads -> each wave does 2 quads (8 waves do 1). ~32 waves/CU.
    const int grid = 2504;
    const int wpg  = grid;

    const size_t need = (size_t)N * (C / 2) * sizeof(unsigned);  // 5.12 MB
    if (ws_size >= need) {
        unsigned* x16 = (unsigned*)d_ws;
        cvt_kernel<<<1024, 256, 0, stream>>>(x, x16, N * (C / 4), N);
        fspool_kernel<true><<<grid, 256, 0, stream>>>(x, x16, col, weight, out, N, wpg);
    } else {
        fspool_kernel<false><<<grid, 256, 0, stream>>>(x, nullptr, col, weight, out, N, wpg);
    }
}